// Round 1
// baseline (2507.505 us; speedup 1.0000x reference)
//
#include <hip/hip_runtime.h>
#include <cstddef>

#define Wn 12
#define Nn 20000
#define Cn 64
#define En 320000

__device__ __forceinline__ float elu_f(float v) {
    return v > 0.f ? v : (expf(v) - 1.f);
}

// ---------------------------------------------------------------------------
// Inception gated temporal conv. One block = 4 nodes. Wave i (of 4) handles
// kernel-size block i (k = 1,3,5,7) for all 4 nodes -> no intra-wave k
// divergence. LDS row stride 68 so the 4-way nl split lands on 2 banks
// (2-way conflict = free per m136).
// ---------------------------------------------------------------------------
template<int K>
__device__ __forceinline__ void incep_core(
    const float* __restrict__ xsn,   // &xs[nl][0][0], row stride 68
    const float* __restrict__ swp,   // sig weights + ocl*Cn*K
    const float* __restrict__ gwp,   // gate weights + ocl*Cn*K
    float* accs, float* accg)
{
    constexpr int P = (K - 1) / 2;
    for (int ic = 0; ic < Cn; ++ic) {
        float xe[Wn + K - 1];        // extended (zero-padded) time row
        #pragma unroll
        for (int i = 0; i < Wn + K - 1; ++i) {
            int wp = i - P;
            xe[i] = (wp >= 0 && wp < Wn) ? xsn[wp * 68 + ic] : 0.f;
        }
        #pragma unroll
        for (int t = 0; t < K; ++t) {
            float wsv = swp[ic * K + t];
            float wgv = gwp[ic * K + t];
            #pragma unroll
            for (int w = 0; w < Wn; ++w) {
                accs[w] = fmaf(xe[w + t], wsv, accs[w]);
                accg[w] = fmaf(xe[w + t], wgv, accg[w]);
            }
        }
    }
}

__global__ __launch_bounds__(256) void inception_kernel(
    const float* __restrict__ x,
    const float* __restrict__ sw1, const float* __restrict__ sb1,
    const float* __restrict__ gw1, const float* __restrict__ gb1,
    const float* __restrict__ sw3, const float* __restrict__ sb3,
    const float* __restrict__ gw3, const float* __restrict__ gb3,
    const float* __restrict__ sw5, const float* __restrict__ sb5,
    const float* __restrict__ gw5, const float* __restrict__ gb5,
    const float* __restrict__ sw7, const float* __restrict__ sb7,
    const float* __restrict__ gw7, const float* __restrict__ gb7,
    float* __restrict__ h)
{
    __shared__ float xs[4][Wn][68];
    const int tid = threadIdx.x;
    const int nb = blockIdx.x * 4;

    for (int idx = tid; idx < 4 * Wn * Cn; idx += 256) {
        int nl  = idx / (Wn * Cn);
        int rem = idx - nl * (Wn * Cn);
        int w = rem >> 6;
        int c = rem & 63;
        xs[nl][w][c] = x[((size_t)w * Nn + nb + nl) * Cn + c];
    }
    __syncthreads();

    const int wave = tid >> 6;      // = kernel-size block 0..3
    const int lane = tid & 63;
    const int ocl  = lane & 15;
    const int nl   = lane >> 4;
    const float* xsn = &xs[nl][0][0];

    float bs, bg;
    switch (wave) {
      case 0:  bs = sb1[ocl]; bg = gb1[ocl]; break;
      case 1:  bs = sb3[ocl]; bg = gb3[ocl]; break;
      case 2:  bs = sb5[ocl]; bg = gb5[ocl]; break;
      default: bs = sb7[ocl]; bg = gb7[ocl]; break;
    }
    float accs[Wn], accg[Wn];
    #pragma unroll
    for (int w = 0; w < Wn; ++w) { accs[w] = bs; accg[w] = bg; }

    switch (wave) {
      case 0:  incep_core<1>(xsn, sw1 + ocl * Cn * 1, gw1 + ocl * Cn * 1, accs, accg); break;
      case 1:  incep_core<3>(xsn, sw3 + ocl * Cn * 3, gw3 + ocl * Cn * 3, accs, accg); break;
      case 2:  incep_core<5>(xsn, sw5 + ocl * Cn * 5, gw5 + ocl * Cn * 5, accs, accg); break;
      default: incep_core<7>(xsn, sw7 + ocl * Cn * 7, gw7 + ocl * Cn * 7, accs, accg); break;
    }

    const int n  = nb + nl;
    const int oc = wave * 16 + ocl;
    #pragma unroll
    for (int w = 0; w < Wn; ++w) {
        float s = accs[w];
        float g = accg[w];
        float r  = s > 0.f ? s : 0.f;
        float sg = 1.f / (1.f + expf(-g));
        h[((size_t)w * Nn + n) * Cn + oc] = r * sg;
    }
}

// ---------------------------------------------------------------------------
// Per-window (N x 64) @ (64 x 64). Block = 4 nodes x 64 out-channels.
// wm[ic][lane]: consecutive lanes -> 2-way bank alias (free).
// hr[nl][ic]: wave-uniform -> LDS broadcast (free).
// ---------------------------------------------------------------------------
__global__ __launch_bounds__(256) void matmul_kernel(
    const float* __restrict__ h, const float* __restrict__ gw,
    float* __restrict__ t)
{
    const int w  = blockIdx.y;
    const int nb = blockIdx.x * 4;
    __shared__ float wm[Cn][Cn];
    __shared__ float hr[4][Cn];
    const int tid = threadIdx.x;

    const float* wsrc = gw + (size_t)w * Cn * Cn;
    for (int idx = tid; idx < Cn * Cn; idx += 256)
        wm[idx >> 6][idx & 63] = wsrc[idx];
    for (int idx = tid; idx < 4 * Cn; idx += 256)
        hr[idx >> 6][idx & 63] = h[((size_t)w * Nn + nb + (idx >> 6)) * Cn + (idx & 63)];
    __syncthreads();

    const int nl = tid >> 6, lane = tid & 63;
    float acc = 0.f;
    #pragma unroll
    for (int ic = 0; ic < Cn; ++ic)
        acc = fmaf(hr[nl][ic], wm[ic][lane], acc);
    t[((size_t)w * Nn + nb + nl) * Cn + lane] = acc;
}

// ---------------------------------------------------------------------------
// Edge scatter: one wave per edge. lane = channel. Gather (coalesced 256 B)
// and atomicAdd (coalesced 256 B). src/dst/ew loads are wave-uniform.
// ---------------------------------------------------------------------------
__global__ __launch_bounds__(256) void scatter_kernel(
    const float* __restrict__ t, const int* __restrict__ ei,
    const float* __restrict__ ew, float* __restrict__ agg)
{
    const int w    = blockIdx.y;
    const int e    = blockIdx.x * 4 + (threadIdx.x >> 6);
    const int lane = threadIdx.x & 63;
    const int* eis = ei + (size_t)w * 2 * En;
    const int src = eis[e];
    const int dst = eis[En + e];
    const float wt = ew[(size_t)w * En + e];
    const float v = t[((size_t)w * Nn + src) * Cn + lane] * wt;
    atomicAdd(&agg[((size_t)w * Nn + dst) * Cn + lane], v);
}

__global__ __launch_bounds__(256) void elu_kernel(
    float* __restrict__ agg, const float* __restrict__ b)
{
    const size_t i = (size_t)blockIdx.x * 256 + threadIdx.x;
    const int    c = (int)(i & 63);
    const size_t w = i / ((size_t)Nn * Cn);
    agg[i] = elu_f(agg[i] + b[w * Cn + c]);
}

__global__ __launch_bounds__(256) void elu_add_kernel(
    const float* __restrict__ agg, const float* __restrict__ b,
    const float* __restrict__ x, float* __restrict__ out)
{
    const size_t i = (size_t)blockIdx.x * 256 + threadIdx.x;
    const int    c = (int)(i & 63);
    const size_t w = i / ((size_t)Nn * Cn);
    out[i] = elu_f(agg[i] + b[w * Cn + c]) + x[i];
}

// ---------------------------------------------------------------------------
// Sequence (single 61.4 MB ws buffer, ping-pong with d_out):
//   inception: x -> ws0                (h0)
//   hop0: matmul ws0 -> out (t0); memset ws0; scatter out->ws0 (agg0);
//         elu in-place ws0             (h1)
//   hop1: matmul ws0 -> out (t1); memset ws0; scatter out->ws0 (agg1);
//         elu_add ws0 + b + x -> out
// ---------------------------------------------------------------------------
extern "C" void kernel_launch(void* const* d_in, const int* in_sizes, int n_in,
                              void* d_out, int out_size, void* d_ws, size_t ws_size,
                              hipStream_t stream)
{
    const float* x    = (const float*)d_in[0];
    const int*   ei   = (const int*)d_in[1];
    const float* ew   = (const float*)d_in[2];
    const float* sw1  = (const float*)d_in[3];
    const float* sb1  = (const float*)d_in[4];
    const float* gw1  = (const float*)d_in[5];
    const float* gb1  = (const float*)d_in[6];
    const float* sw3  = (const float*)d_in[7];
    const float* sb3  = (const float*)d_in[8];
    const float* gw3  = (const float*)d_in[9];
    const float* gb3  = (const float*)d_in[10];
    const float* sw5  = (const float*)d_in[11];
    const float* sb5  = (const float*)d_in[12];
    const float* gw5  = (const float*)d_in[13];
    const float* gb5  = (const float*)d_in[14];
    const float* sw7  = (const float*)d_in[15];
    const float* sb7  = (const float*)d_in[16];
    const float* gw7  = (const float*)d_in[17];
    const float* gb7  = (const float*)d_in[18];
    const float* gcnw = (const float*)d_in[19];
    const float* gcnb = (const float*)d_in[20];
    float* out = (float*)d_out;
    float* ws0 = (float*)d_ws;

    const size_t WNC = (size_t)Wn * Nn * Cn;

    inception_kernel<<<Nn / 4, 256, 0, stream>>>(
        x, sw1, sb1, gw1, gb1, sw3, sb3, gw3, gb3,
        sw5, sb5, gw5, gb5, sw7, sb7, gw7, gb7, ws0);

    // hop 0
    matmul_kernel<<<dim3(Nn / 4, Wn), 256, 0, stream>>>(ws0, gcnw, out);
    hipMemsetAsync(ws0, 0, WNC * sizeof(float), stream);
    scatter_kernel<<<dim3(En / 4, Wn), 256, 0, stream>>>(out, ei, ew, ws0);
    elu_kernel<<<(int)(WNC / 256), 256, 0, stream>>>(ws0, gcnb);

    // hop 1
    matmul_kernel<<<dim3(Nn / 4, Wn), 256, 0, stream>>>(ws0, gcnw + (size_t)Wn * Cn * Cn, out);
    hipMemsetAsync(ws0, 0, WNC * sizeof(float), stream);
    scatter_kernel<<<dim3(En / 4, Wn), 256, 0, stream>>>(out, ei, ew, ws0);
    elu_add_kernel<<<(int)(WNC / 256), 256, 0, stream>>>(ws0, gcnb + (size_t)Wn * Cn, x, out);
}

// Round 2
// 1748.648 us; speedup vs baseline: 1.4340x; 1.4340x over previous
//
#include <hip/hip_runtime.h>
#include <cstddef>

#define Wn 12
#define Nn 20000
#define Cn 64
#define En 320000
#define OFFS_STRIDE 20032   // padded N+1 stride for per-window offset tables

__device__ __forceinline__ float elu_f(float v) {
    return v > 0.f ? v : (expf(v) - 1.f);
}

// ---------------------------------------------------------------------------
// Inception gated temporal conv (unchanged from round 1).
// ---------------------------------------------------------------------------
template<int K>
__device__ __forceinline__ void incep_core(
    const float* __restrict__ xsn,
    const float* __restrict__ swp,
    const float* __restrict__ gwp,
    float* accs, float* accg)
{
    constexpr int P = (K - 1) / 2;
    for (int ic = 0; ic < Cn; ++ic) {
        float xe[Wn + K - 1];
        #pragma unroll
        for (int i = 0; i < Wn + K - 1; ++i) {
            int wp = i - P;
            xe[i] = (wp >= 0 && wp < Wn) ? xsn[wp * 68 + ic] : 0.f;
        }
        #pragma unroll
        for (int t = 0; t < K; ++t) {
            float wsv = swp[ic * K + t];
            float wgv = gwp[ic * K + t];
            #pragma unroll
            for (int w = 0; w < Wn; ++w) {
                accs[w] = fmaf(xe[w + t], wsv, accs[w]);
                accg[w] = fmaf(xe[w + t], wgv, accg[w]);
            }
        }
    }
}

__global__ __launch_bounds__(256) void inception_kernel(
    const float* __restrict__ x,
    const float* __restrict__ sw1, const float* __restrict__ sb1,
    const float* __restrict__ gw1, const float* __restrict__ gb1,
    const float* __restrict__ sw3, const float* __restrict__ sb3,
    const float* __restrict__ gw3, const float* __restrict__ gb3,
    const float* __restrict__ sw5, const float* __restrict__ sb5,
    const float* __restrict__ gw5, const float* __restrict__ gb5,
    const float* __restrict__ sw7, const float* __restrict__ sb7,
    const float* __restrict__ gw7, const float* __restrict__ gb7,
    float* __restrict__ h)
{
    __shared__ float xs[4][Wn][68];
    const int tid = threadIdx.x;
    const int nb = blockIdx.x * 4;

    for (int idx = tid; idx < 4 * Wn * Cn; idx += 256) {
        int nl  = idx / (Wn * Cn);
        int rem = idx - nl * (Wn * Cn);
        int w = rem >> 6;
        int c = rem & 63;
        xs[nl][w][c] = x[((size_t)w * Nn + nb + nl) * Cn + c];
    }
    __syncthreads();

    const int wave = tid >> 6;
    const int lane = tid & 63;
    const int ocl  = lane & 15;
    const int nl   = lane >> 4;
    const float* xsn = &xs[nl][0][0];

    float bs, bg;
    switch (wave) {
      case 0:  bs = sb1[ocl]; bg = gb1[ocl]; break;
      case 1:  bs = sb3[ocl]; bg = gb3[ocl]; break;
      case 2:  bs = sb5[ocl]; bg = gb5[ocl]; break;
      default: bs = sb7[ocl]; bg = gb7[ocl]; break;
    }
    float accs[Wn], accg[Wn];
    #pragma unroll
    for (int w = 0; w < Wn; ++w) { accs[w] = bs; accg[w] = bg; }

    switch (wave) {
      case 0:  incep_core<1>(xsn, sw1 + ocl * Cn * 1, gw1 + ocl * Cn * 1, accs, accg); break;
      case 1:  incep_core<3>(xsn, sw3 + ocl * Cn * 3, gw3 + ocl * Cn * 3, accs, accg); break;
      case 2:  incep_core<5>(xsn, sw5 + ocl * Cn * 5, gw5 + ocl * Cn * 5, accs, accg); break;
      default: incep_core<7>(xsn, sw7 + ocl * Cn * 7, gw7 + ocl * Cn * 7, accs, accg); break;
    }

    const int n  = nb + nl;
    const int oc = wave * 16 + ocl;
    #pragma unroll
    for (int w = 0; w < Wn; ++w) {
        float s = accs[w];
        float g = accg[w];
        float r  = s > 0.f ? s : 0.f;
        float sg = 1.f / (1.f + expf(-g));
        h[((size_t)w * Nn + n) * Cn + oc] = r * sg;
    }
}

// ---------------------------------------------------------------------------
// Per-window (N x 64) @ (64 x 64) matmul (unchanged).
// ---------------------------------------------------------------------------
__global__ __launch_bounds__(256) void matmul_kernel(
    const float* __restrict__ h, const float* __restrict__ gw,
    float* __restrict__ t)
{
    const int w  = blockIdx.y;
    const int nb = blockIdx.x * 4;
    __shared__ float wm[Cn][Cn];
    __shared__ float hr[4][Cn];
    const int tid = threadIdx.x;

    const float* wsrc = gw + (size_t)w * Cn * Cn;
    for (int idx = tid; idx < Cn * Cn; idx += 256)
        wm[idx >> 6][idx & 63] = wsrc[idx];
    for (int idx = tid; idx < 4 * Cn; idx += 256)
        hr[idx >> 6][idx & 63] = h[((size_t)w * Nn + nb + (idx >> 6)) * Cn + (idx & 63)];
    __syncthreads();

    const int nl = tid >> 6, lane = tid & 63;
    float acc = 0.f;
    #pragma unroll
    for (int ic = 0; ic < Cn; ++ic)
        acc = fmaf(hr[nl][ic], wm[ic][lane], acc);
    t[((size_t)w * Nn + nb + nl) * Cn + lane] = acc;
}

// ---------------------------------------------------------------------------
// Counting-sort-by-dst preamble (runs once per call, reused by both hops).
// ---------------------------------------------------------------------------
__global__ __launch_bounds__(256) void hist_kernel(
    const int* __restrict__ ei, int* __restrict__ deg)
{
    const int w = blockIdx.y;
    const int e = blockIdx.x * 256 + threadIdx.x;
    const int dst = ei[(size_t)w * 2 * En + En + e];
    atomicAdd(&deg[w * Nn + dst], 1);
}

// One wave per window: exclusive scan of 20000 degrees -> offsets + cursors.
__global__ __launch_bounds__(64) void scan_kernel(
    const int* __restrict__ deg, int* __restrict__ offs, int* __restrict__ curs)
{
    const int w = blockIdx.x;
    const int lane = threadIdx.x;
    int running = 0;
    for (int base = 0; base < Nn; base += 64) {
        const int i = base + lane;
        int v = (i < Nn) ? deg[w * Nn + i] : 0;
        // inclusive wave scan
        int sum = v;
        #pragma unroll
        for (int d = 1; d < 64; d <<= 1) {
            int t = __shfl_up(sum, d);
            if (lane >= d) sum += t;
        }
        const int excl = sum - v;
        if (i < Nn) {
            offs[w * OFFS_STRIDE + i] = running + excl;
            curs[w * Nn + i]          = running + excl;
        }
        running += __shfl(sum, 63);
    }
    if (lane == 0) offs[w * OFFS_STRIDE + Nn] = running;
}

// Scatter (src, weight) pairs into dst-sorted order.
__global__ __launch_bounds__(256) void sortpairs_kernel(
    const int* __restrict__ ei, const float* __restrict__ ew,
    int* __restrict__ curs, float2* __restrict__ pairs)
{
    const int w = blockIdx.y;
    const int e = blockIdx.x * 256 + threadIdx.x;
    const int* eis = ei + (size_t)w * 2 * En;
    const int src = eis[e];
    const int dst = eis[En + e];
    const float wt = ew[(size_t)w * En + e];
    const int pos = atomicAdd(&curs[w * Nn + dst], 1);
    pairs[(size_t)w * En + pos] = make_float2(__int_as_float(src), wt);
}

// ---------------------------------------------------------------------------
// Atomic-free aggregation: one wave per dst node, lane = channel.
// Gathers t[src] (coalesced 256 B), accumulates in registers, fused
// bias + ELU (+x residual on last hop), one plain 256 B store.
// ---------------------------------------------------------------------------
template<bool LAST>
__global__ __launch_bounds__(256) void agg_kernel(
    const float* __restrict__ t, const float2* __restrict__ pairs,
    const int* __restrict__ offs, const float* __restrict__ b,
    const float* __restrict__ x, float* __restrict__ out)
{
    const int w    = blockIdx.y;
    const int d    = blockIdx.x * 4 + (threadIdx.x >> 6);
    const int lane = threadIdx.x & 63;
    const int* ow  = offs + w * OFFS_STRIDE;
    const int beg = ow[d];
    const int end = ow[d + 1];
    const float2* pw = pairs + (size_t)w * En;
    const float*  tw = t + (size_t)w * Nn * Cn;

    float acc = 0.f;
    int i = beg;
    for (; i + 2 <= end; i += 2) {
        float2 p0 = pw[i];
        float2 p1 = pw[i + 1];
        const float v0 = tw[(size_t)__float_as_int(p0.x) * Cn + lane];
        const float v1 = tw[(size_t)__float_as_int(p1.x) * Cn + lane];
        acc = fmaf(p0.y, v0, acc);
        acc = fmaf(p1.y, v1, acc);
    }
    if (i < end) {
        float2 p0 = pw[i];
        acc = fmaf(p0.y, tw[(size_t)__float_as_int(p0.x) * Cn + lane], acc);
    }

    float v = elu_f(acc + b[w * Cn + lane]);
    const size_t oi = ((size_t)w * Nn + d) * Cn + lane;
    if (LAST) v += x[oi];
    out[oi] = v;
}

// ---------------------------------------------------------------------------
// Fallback (round-1 atomic path) kernels, used only if ws_size is too small.
// ---------------------------------------------------------------------------
__global__ __launch_bounds__(256) void scatter_kernel(
    const float* __restrict__ t, const int* __restrict__ ei,
    const float* __restrict__ ew, float* __restrict__ agg)
{
    const int w    = blockIdx.y;
    const int e    = blockIdx.x * 4 + (threadIdx.x >> 6);
    const int lane = threadIdx.x & 63;
    const int* eis = ei + (size_t)w * 2 * En;
    const int src = eis[e];
    const int dst = eis[En + e];
    const float wt = ew[(size_t)w * En + e];
    const float v = t[((size_t)w * Nn + src) * Cn + lane] * wt;
    atomicAdd(&agg[((size_t)w * Nn + dst) * Cn + lane], v);
}

__global__ __launch_bounds__(256) void elu_kernel(
    float* __restrict__ agg, const float* __restrict__ b)
{
    const size_t i = (size_t)blockIdx.x * 256 + threadIdx.x;
    const int    c = (int)(i & 63);
    const size_t w = i / ((size_t)Nn * Cn);
    agg[i] = elu_f(agg[i] + b[w * Cn + c]);
}

__global__ __launch_bounds__(256) void elu_add_kernel(
    const float* __restrict__ agg, const float* __restrict__ b,
    const float* __restrict__ x, float* __restrict__ out)
{
    const size_t i = (size_t)blockIdx.x * 256 + threadIdx.x;
    const int    c = (int)(i & 63);
    const size_t w = i / ((size_t)Nn * Cn);
    out[i] = elu_f(agg[i] + b[w * Cn + c]) + x[i];
}

// ---------------------------------------------------------------------------
// ws layout (sort path), floats:
//   [0)                 pairs   : 2*W*E      = 7,680,000
//   [7,680,000)         offs    : W*20032    =   240,384 (int)
//   [7,920,384)         curs    : W*Nn       =   240,000 (int)
//   [8,160,384)         deg     : W*Nn       =   240,000 (int)
//   [8,400,384)         H       : W*Nn*Cn    = 15,360,000
// total 23,760,384 floats = 95,041,536 B
// ---------------------------------------------------------------------------
extern "C" void kernel_launch(void* const* d_in, const int* in_sizes, int n_in,
                              void* d_out, int out_size, void* d_ws, size_t ws_size,
                              hipStream_t stream)
{
    const float* x    = (const float*)d_in[0];
    const int*   ei   = (const int*)d_in[1];
    const float* ew   = (const float*)d_in[2];
    const float* sw1  = (const float*)d_in[3];
    const float* sb1  = (const float*)d_in[4];
    const float* gw1  = (const float*)d_in[5];
    const float* gb1  = (const float*)d_in[6];
    const float* sw3  = (const float*)d_in[7];
    const float* sb3  = (const float*)d_in[8];
    const float* gw3  = (const float*)d_in[9];
    const float* gb3  = (const float*)d_in[10];
    const float* sw5  = (const float*)d_in[11];
    const float* sb5  = (const float*)d_in[12];
    const float* gw5  = (const float*)d_in[13];
    const float* gb5  = (const float*)d_in[14];
    const float* sw7  = (const float*)d_in[15];
    const float* sb7  = (const float*)d_in[16];
    const float* gw7  = (const float*)d_in[17];
    const float* gb7  = (const float*)d_in[18];
    const float* gcnw = (const float*)d_in[19];
    const float* gcnb = (const float*)d_in[20];
    float* out = (float*)d_out;

    const size_t WNC = (size_t)Wn * Nn * Cn;
    const size_t need = (size_t)(7680000 + 240384 + 240000 + 240000 + 15360000) * 4;

    if (ws_size >= need) {
        float2* pairs = (float2*)d_ws;
        int*    offs  = (int*)((float*)d_ws + 7680000);
        int*    curs  = offs + 240384;
        int*    deg   = curs + 240000;
        float*  H     = (float*)(deg + 240000);

        // --- sort preamble (edge_index shared by both hops) ---
        hipMemsetAsync(deg, 0, (size_t)Wn * Nn * sizeof(int), stream);
        hist_kernel<<<dim3(En / 256, Wn), 256, 0, stream>>>(ei, deg);
        scan_kernel<<<Wn, 64, 0, stream>>>(deg, offs, curs);
        sortpairs_kernel<<<dim3(En / 256, Wn), 256, 0, stream>>>(ei, ew, curs, pairs);

        // --- feature path ---
        inception_kernel<<<Nn / 4, 256, 0, stream>>>(
            x, sw1, sb1, gw1, gb1, sw3, sb3, gw3, gb3,
            sw5, sb5, gw5, gb5, sw7, sb7, gw7, gb7, H);

        // hop 0: t0 = H @ W0 -> out; agg(out) -> H (fused bias+elu)
        matmul_kernel<<<dim3(Nn / 4, Wn), 256, 0, stream>>>(H, gcnw, out);
        agg_kernel<false><<<dim3(Nn / 4, Wn), 256, 0, stream>>>(
            out, pairs, offs, gcnb, nullptr, H);

        // hop 1: t1 = H @ W1 -> out; agg(out) -> H (fused bias+elu+x); copy to out
        matmul_kernel<<<dim3(Nn / 4, Wn), 256, 0, stream>>>(
            H, gcnw + (size_t)Wn * Cn * Cn, out);
        agg_kernel<true><<<dim3(Nn / 4, Wn), 256, 0, stream>>>(
            out, pairs, offs, gcnb + (size_t)Wn * Cn, x, H);
        hipMemcpyAsync(out, H, WNC * sizeof(float), hipMemcpyDeviceToDevice, stream);
    } else {
        // ---- fallback: round-1 atomic path (needs only the 61.4 MB H buffer) ----
        float* ws0 = (float*)d_ws;
        inception_kernel<<<Nn / 4, 256, 0, stream>>>(
            x, sw1, sb1, gw1, gb1, sw3, sb3, gw3, gb3,
            sw5, sb5, gw5, gb5, sw7, sb7, gw7, gb7, ws0);

        matmul_kernel<<<dim3(Nn / 4, Wn), 256, 0, stream>>>(ws0, gcnw, out);
        hipMemsetAsync(ws0, 0, WNC * sizeof(float), stream);
        scatter_kernel<<<dim3(En / 4, Wn), 256, 0, stream>>>(out, ei, ew, ws0);
        elu_kernel<<<(int)(WNC / 256), 256, 0, stream>>>(ws0, gcnb);

        matmul_kernel<<<dim3(Nn / 4, Wn), 256, 0, stream>>>(ws0, gcnw + (size_t)Wn * Cn * Cn, out);
        hipMemsetAsync(ws0, 0, WNC * sizeof(float), stream);
        scatter_kernel<<<dim3(En / 4, Wn), 256, 0, stream>>>(out, ei, ew, ws0);
        elu_add_kernel<<<(int)(WNC / 256), 256, 0, stream>>>(ws0, gcnb + (size_t)Wn * Cn, x, out);
    }
}

// Round 3
// 1711.563 us; speedup vs baseline: 1.4650x; 1.0217x over previous
//
#include <hip/hip_runtime.h>
#include <cstddef>

#define Wn 12
#define Nn 20000
#define Cn 64
#define En 320000
#define OFFS_STRIDE 20032

__device__ __forceinline__ float elu_f(float v) {
    return v > 0.f ? v : (expf(v) - 1.f);
}

// ---------------------------------------------------------------------------
// Weight transpose: [oc][ic][t] -> [oc][t][ic]  (sig block then gate block).
// Tiny; runs once per call into dead ws space.
// ---------------------------------------------------------------------------
__global__ __launch_bounds__(256) void transw_kernel(
    const float* __restrict__ swv, const float* __restrict__ gwv,
    float* __restrict__ dst, int K)
{
    const int tot = 16 * 64 * K;
    for (int i = threadIdx.x + blockIdx.x * 256; i < 2 * tot; i += gridDim.x * 256) {
        const float* srcp = (i < tot) ? swv : gwv;
        int j  = (i < tot) ? i : i - tot;
        int oc = j / (64 * K);
        int r  = j - oc * 64 * K;     // t*64 + ic
        int t  = r >> 6;
        int ic = r & 63;
        dst[i] = srcp[(oc * 64 + ic) * K + t];
    }
}

// ---------------------------------------------------------------------------
// Inception gated temporal conv, vectorized.
// Block = 4 nodes, wave = K-group, lane: ocl = lane&15 (out channel),
// nl = lane>>4 (node). LDS x layout [node][w][ic] with row stride 80 floats
// (16B aligned, +16 bank offset per row) and node stride 968 floats
// (+8 bank offset per node -> the 4 nl addresses hit disjoint banks).
// Inner loop: ds_read_b128 of 4 input channels, float4 weight loads from the
// pre-transposed [oc][t][ic] table, 96 register FMAs per (ic-block, t).
// ---------------------------------------------------------------------------
template<int K>
__device__ __forceinline__ void incep_v4(
    const float4* __restrict__ xq,      // node plane (float4 units), idx w*20+icb
    const float4* __restrict__ swT,     // + ocl*K*16 already applied
    const float4* __restrict__ gwT,
    float* accs, float* accg)
{
    constexpr int P = (K - 1) / 2;
    for (int icb = 0; icb < 16; ++icb) {
        float4 xr[Wn];
        #pragma unroll
        for (int w = 0; w < Wn; ++w) xr[w] = xq[w * 20 + icb];
        #pragma unroll
        for (int t = 0; t < K; ++t) {
            const float4 wsv = swT[t * 16 + icb];
            const float4 wgv = gwT[t * 16 + icb];
            #pragma unroll
            for (int w = 0; w < Wn; ++w) {
                const int wp = w + t - P;
                if (wp >= 0 && wp < Wn) {
                    const float4 xv = xr[wp];
                    accs[w] = fmaf(xv.x, wsv.x, accs[w]);
                    accs[w] = fmaf(xv.y, wsv.y, accs[w]);
                    accs[w] = fmaf(xv.z, wsv.z, accs[w]);
                    accs[w] = fmaf(xv.w, wsv.w, accs[w]);
                    accg[w] = fmaf(xv.x, wgv.x, accg[w]);
                    accg[w] = fmaf(xv.y, wgv.y, accg[w]);
                    accg[w] = fmaf(xv.z, wgv.z, accg[w]);
                    accg[w] = fmaf(xv.w, wgv.w, accg[w]);
                }
            }
        }
    }
}

__global__ __launch_bounds__(256) void inception_kernel(
    const float* __restrict__ x,
    const float* __restrict__ sb1, const float* __restrict__ gb1,
    const float* __restrict__ sb3, const float* __restrict__ gb3,
    const float* __restrict__ sb5, const float* __restrict__ gb5,
    const float* __restrict__ sb7, const float* __restrict__ gb7,
    const float* __restrict__ wT,   // transposed weights, layout per group
    float* __restrict__ h)
{
    __shared__ float4 xs4[4 * 242];          // 968 floats per node plane
    const int tid = threadIdx.x;
    const int nb = blockIdx.x * 4;

    const float4* xg = (const float4*)x;
    for (int idx = tid; idx < 768; idx += 256) {
        int nl  = idx / 192;
        int rem = idx - nl * 192;
        int w  = rem >> 4;
        int c4 = rem & 15;
        xs4[nl * 242 + w * 20 + c4] = xg[((size_t)w * Nn + nb + nl) * 16 + c4];
    }
    __syncthreads();

    const int wave = tid >> 6;
    const int lane = tid & 63;
    const int ocl  = lane & 15;
    const int nl   = lane >> 4;
    const float4* xq  = xs4 + nl * 242;
    const float4* wT4 = (const float4*)wT;

    float bs, bg;
    switch (wave) {
      case 0:  bs = sb1[ocl]; bg = gb1[ocl]; break;
      case 1:  bs = sb3[ocl]; bg = gb3[ocl]; break;
      case 2:  bs = sb5[ocl]; bg = gb5[ocl]; break;
      default: bs = sb7[ocl]; bg = gb7[ocl]; break;
    }
    float accs[Wn], accg[Wn];
    #pragma unroll
    for (int w = 0; w < Wn; ++w) { accs[w] = bs; accg[w] = bg; }

    // float4-unit offsets: g0 sig 0 gate 256 | g1 512/1280 | g2 2048/3328 | g3 4608/6400
    switch (wave) {
      case 0:  incep_v4<1>(xq, wT4 + 0    + ocl * 16,  wT4 + 256  + ocl * 16,  accs, accg); break;
      case 1:  incep_v4<3>(xq, wT4 + 512  + ocl * 48,  wT4 + 1280 + ocl * 48,  accs, accg); break;
      case 2:  incep_v4<5>(xq, wT4 + 2048 + ocl * 80,  wT4 + 3328 + ocl * 80,  accs, accg); break;
      default: incep_v4<7>(xq, wT4 + 4608 + ocl * 112, wT4 + 6400 + ocl * 112, accs, accg); break;
    }

    const int n  = nb + nl;
    const int oc = wave * 16 + ocl;
    #pragma unroll
    for (int w = 0; w < Wn; ++w) {
        float s = accs[w];
        float g = accg[w];
        float r  = s > 0.f ? s : 0.f;
        float sg = 1.f / (1.f + expf(-g));
        h[((size_t)w * Nn + n) * Cn + oc] = r * sg;
    }
}

// ---------------------------------------------------------------------------
// Per-window (N x 64) @ (64 x 64) matmul (unchanged).
// ---------------------------------------------------------------------------
__global__ __launch_bounds__(256) void matmul_kernel(
    const float* __restrict__ h, const float* __restrict__ gw,
    float* __restrict__ t)
{
    const int w  = blockIdx.y;
    const int nb = blockIdx.x * 4;
    __shared__ float wm[Cn][Cn];
    __shared__ float hr[4][Cn];
    const int tid = threadIdx.x;

    const float* wsrc = gw + (size_t)w * Cn * Cn;
    for (int idx = tid; idx < Cn * Cn; idx += 256)
        wm[idx >> 6][idx & 63] = wsrc[idx];
    for (int idx = tid; idx < 4 * Cn; idx += 256)
        hr[idx >> 6][idx & 63] = h[((size_t)w * Nn + nb + (idx >> 6)) * Cn + (idx & 63)];
    __syncthreads();

    const int nl = tid >> 6, lane = tid & 63;
    float acc = 0.f;
    #pragma unroll
    for (int ic = 0; ic < Cn; ++ic)
        acc = fmaf(hr[nl][ic], wm[ic][lane], acc);
    t[((size_t)w * Nn + nb + nl) * Cn + lane] = acc;
}

// ---------------------------------------------------------------------------
// Counting-sort-by-dst preamble (unchanged).
// ---------------------------------------------------------------------------
__global__ __launch_bounds__(256) void hist_kernel(
    const int* __restrict__ ei, int* __restrict__ deg)
{
    const int w = blockIdx.y;
    const int e = blockIdx.x * 256 + threadIdx.x;
    const int dst = ei[(size_t)w * 2 * En + En + e];
    atomicAdd(&deg[w * Nn + dst], 1);
}

__global__ __launch_bounds__(64) void scan_kernel(
    const int* __restrict__ deg, int* __restrict__ offs, int* __restrict__ curs)
{
    const int w = blockIdx.x;
    const int lane = threadIdx.x;
    int running = 0;
    for (int base = 0; base < Nn; base += 64) {
        const int i = base + lane;
        int v = (i < Nn) ? deg[w * Nn + i] : 0;
        int sum = v;
        #pragma unroll
        for (int d = 1; d < 64; d <<= 1) {
            int t = __shfl_up(sum, d);
            if (lane >= d) sum += t;
        }
        const int excl = sum - v;
        if (i < Nn) {
            offs[w * OFFS_STRIDE + i] = running + excl;
            curs[w * Nn + i]          = running + excl;
        }
        running += __shfl(sum, 63);
    }
    if (lane == 0) offs[w * OFFS_STRIDE + Nn] = running;
}

__global__ __launch_bounds__(256) void sortpairs_kernel(
    const int* __restrict__ ei, const float* __restrict__ ew,
    int* __restrict__ curs, float2* __restrict__ pairs)
{
    const int w = blockIdx.y;
    const int e = blockIdx.x * 256 + threadIdx.x;
    const int* eis = ei + (size_t)w * 2 * En;
    const int src = eis[e];
    const int dst = eis[En + e];
    const float wt = ew[(size_t)w * En + e];
    const int pos = atomicAdd(&curs[w * Nn + dst], 1);
    pairs[(size_t)w * En + pos] = make_float2(__int_as_float(src), wt);
}

// ---------------------------------------------------------------------------
// Atomic-free aggregation (unchanged): one wave per dst node, lane = channel.
// ---------------------------------------------------------------------------
template<bool LAST>
__global__ __launch_bounds__(256) void agg_kernel(
    const float* __restrict__ t, const float2* __restrict__ pairs,
    const int* __restrict__ offs, const float* __restrict__ b,
    const float* __restrict__ x, float* __restrict__ out)
{
    const int w    = blockIdx.y;
    const int d    = blockIdx.x * 4 + (threadIdx.x >> 6);
    const int lane = threadIdx.x & 63;
    const int* ow  = offs + w * OFFS_STRIDE;
    const int beg = ow[d];
    const int end = ow[d + 1];
    const float2* pw = pairs + (size_t)w * En;
    const float*  tw = t + (size_t)w * Nn * Cn;

    float acc = 0.f;
    int i = beg;
    for (; i + 2 <= end; i += 2) {
        float2 p0 = pw[i];
        float2 p1 = pw[i + 1];
        const float v0 = tw[(size_t)__float_as_int(p0.x) * Cn + lane];
        const float v1 = tw[(size_t)__float_as_int(p1.x) * Cn + lane];
        acc = fmaf(p0.y, v0, acc);
        acc = fmaf(p1.y, v1, acc);
    }
    if (i < end) {
        float2 p0 = pw[i];
        acc = fmaf(p0.y, tw[(size_t)__float_as_int(p0.x) * Cn + lane], acc);
    }

    float v = elu_f(acc + b[w * Cn + lane]);
    const size_t oi = ((size_t)w * Nn + d) * Cn + lane;
    if (LAST) v += x[oi];
    out[oi] = v;
}

// ---------------------------------------------------------------------------
// ws layout (floats):
//   [0)          pairs : 7,680,000
//   [7,680,000)  offs  :   240,384 (int)
//   [7,920,384)  curs  :   240,000 (int)
//   [8,160,384)  deg   :   240,000 (int)  -- reused as wT (32,768 floats)
//                                            after scan_kernel's last read
//   [8,400,384)  H     : 15,360,000
// ---------------------------------------------------------------------------
extern "C" void kernel_launch(void* const* d_in, const int* in_sizes, int n_in,
                              void* d_out, int out_size, void* d_ws, size_t ws_size,
                              hipStream_t stream)
{
    const float* x    = (const float*)d_in[0];
    const int*   ei   = (const int*)d_in[1];
    const float* ew   = (const float*)d_in[2];
    const float* sw1  = (const float*)d_in[3];
    const float* sb1  = (const float*)d_in[4];
    const float* gw1  = (const float*)d_in[5];
    const float* gb1  = (const float*)d_in[6];
    const float* sw3  = (const float*)d_in[7];
    const float* sb3  = (const float*)d_in[8];
    const float* gw3  = (const float*)d_in[9];
    const float* gb3  = (const float*)d_in[10];
    const float* sw5  = (const float*)d_in[11];
    const float* sb5  = (const float*)d_in[12];
    const float* gw5  = (const float*)d_in[13];
    const float* gb5  = (const float*)d_in[14];
    const float* sw7  = (const float*)d_in[15];
    const float* sb7  = (const float*)d_in[16];
    const float* gw7  = (const float*)d_in[17];
    const float* gb7  = (const float*)d_in[18];
    const float* gcnw = (const float*)d_in[19];
    const float* gcnb = (const float*)d_in[20];
    float* out = (float*)d_out;

    const size_t WNC = (size_t)Wn * Nn * Cn;

    float2* pairs = (float2*)d_ws;
    int*    offs  = (int*)((float*)d_ws + 7680000);
    int*    curs  = offs + 240384;
    int*    deg   = curs + 240000;
    float*  wT    = (float*)deg;          // reused after scan_kernel
    float*  H     = (float*)(deg + 240000);

    // --- sort preamble ---
    hipMemsetAsync(deg, 0, (size_t)Wn * Nn * sizeof(int), stream);
    hist_kernel<<<dim3(En / 256, Wn), 256, 0, stream>>>(ei, deg);
    scan_kernel<<<Wn, 64, 0, stream>>>(deg, offs, curs);          // last read of deg
    sortpairs_kernel<<<dim3(En / 256, Wn), 256, 0, stream>>>(ei, ew, curs, pairs);

    // --- weight transpose into the dead deg region ---
    transw_kernel<<<8, 256, 0, stream>>>(sw1, gw1, wT + 0,     1);
    transw_kernel<<<8, 256, 0, stream>>>(sw3, gw3, wT + 2048,  3);
    transw_kernel<<<8, 256, 0, stream>>>(sw5, gw5, wT + 8192,  5);
    transw_kernel<<<8, 256, 0, stream>>>(sw7, gw7, wT + 18432, 7);

    // --- feature path ---
    inception_kernel<<<Nn / 4, 256, 0, stream>>>(
        x, sb1, gb1, sb3, gb3, sb5, gb5, sb7, gb7, wT, H);

    // hop 0
    matmul_kernel<<<dim3(Nn / 4, Wn), 256, 0, stream>>>(H, gcnw, out);
    agg_kernel<false><<<dim3(Nn / 4, Wn), 256, 0, stream>>>(
        out, pairs, offs, gcnb, nullptr, H);

    // hop 1
    matmul_kernel<<<dim3(Nn / 4, Wn), 256, 0, stream>>>(
        H, gcnw + (size_t)Wn * Cn * Cn, out);
    agg_kernel<true><<<dim3(Nn / 4, Wn), 256, 0, stream>>>(
        out, pairs, offs, gcnb + (size_t)Wn * Cn, x, H);
    hipMemcpyAsync(out, H, WNC * sizeof(float), hipMemcpyDeviceToDevice, stream);
}